// Round 1
// baseline (2034.691 us; speedup 1.0000x reference)
//
#include <hip/hip_runtime.h>
#include <hip/hip_bf16.h>
#include <math.h>

#define DIMX 2048
#define SLEN 2048
#define BSZ 2
#define NHEADS 16
#define HDIM 128
#define FFND 8192
#define CTXL 512
#define LN_EPS 1e-6f

typedef __attribute__((ext_vector_type(8))) short short8_t;
typedef __attribute__((ext_vector_type(4))) float f32x4;
typedef __hip_bfloat16 bf16;

__device__ inline short f2bf(float f) {
  union { float f; unsigned u; } v; v.f = f;
  return (short)((v.u + 0x7FFFu + ((v.u >> 16) & 1u)) >> 16);
}

__device__ inline float wred_sum(float v) {
#pragma unroll
  for (int o = 32; o > 0; o >>= 1) v += __shfl_xor(v, o, 64);
  return v;
}

// em = modulation(1,6,D) + e(B,6,D)
__global__ void em_kernel(const float* __restrict__ e, const float* __restrict__ mod,
                          float* __restrict__ em, int n) {
  int i = blockIdx.x * 256 + threadIdx.x;
  if (i < n) em[i] = e[i] + mod[i % (6 * DIMX)];
}

// LayerNorm (no affine) then y*g + b;  g = addone + gamma[b*gbstride + d]
__global__ __launch_bounds__(256) void ln_kernel(
    const float* __restrict__ x, const float* __restrict__ gamma,
    const float* __restrict__ beta, int gbstride, float addone,
    int rows_per_b, bf16* __restrict__ out) {
  int row = blockIdx.x;
  int t = threadIdx.x;
  const float* xr = x + (size_t)row * DIMX;
  float4 v0 = *(const float4*)(xr + t * 8);
  float4 v1 = *(const float4*)(xr + t * 8 + 4);
  float vv[8] = {v0.x, v0.y, v0.z, v0.w, v1.x, v1.y, v1.z, v1.w};
  float s = 0.f, ss = 0.f;
#pragma unroll
  for (int i = 0; i < 8; ++i) { s += vv[i]; ss += vv[i] * vv[i]; }
  __shared__ float red[8];
  s = wred_sum(s); ss = wred_sum(ss);
  int wid = t >> 6;
  if ((t & 63) == 0) { red[wid] = s; red[4 + wid] = ss; }
  __syncthreads();
  float sum = red[0] + red[1] + red[2] + red[3];
  float sumsq = red[4] + red[5] + red[6] + red[7];
  float mean = sum * (1.f / DIMX);
  float var = sumsq * (1.f / DIMX) - mean * mean;
  float rs = rsqrtf(var + LN_EPS);
  int b = row / rows_per_b;
  const float* g = gamma + (size_t)b * gbstride;
  const float* be = beta + (size_t)b * gbstride;
  short8_t o;
#pragma unroll
  for (int i = 0; i < 8; ++i) {
    int d = t * 8 + i;
    float y = (vv[i] - mean) * rs;
    o[i] = f2bf(y * (addone + g[d]) + be[d]);
  }
  *(short8_t*)((short*)out + (size_t)row * DIMX + t * 8) = o;
}

// RMSNorm over DIM, * w, optional RoPE (per 128-head, pair-interleaved), out bf16
__global__ __launch_bounds__(256) void rms_rope_kernel(
    const float* __restrict__ x, const float* __restrict__ w,
    const float* __restrict__ fcos, const float* __restrict__ fsin,
    int do_rope, bf16* __restrict__ out) {
  int row = blockIdx.x;
  int t = threadIdx.x;
  const float* xr = x + (size_t)row * DIMX;
  float4 v0 = *(const float4*)(xr + t * 8);
  float4 v1 = *(const float4*)(xr + t * 8 + 4);
  float vv[8] = {v0.x, v0.y, v0.z, v0.w, v1.x, v1.y, v1.z, v1.w};
  float ss = 0.f;
#pragma unroll
  for (int i = 0; i < 8; ++i) ss += vv[i] * vv[i];
  __shared__ float red[4];
  ss = wred_sum(ss);
  int wid = t >> 6;
  if ((t & 63) == 0) red[wid] = ss;
  __syncthreads();
  float sumsq = red[0] + red[1] + red[2] + red[3];
  float rs = rsqrtf(sumsq * (1.f / DIMX) + LN_EPS);
  float y[8];
#pragma unroll
  for (int i = 0; i < 8; ++i) y[i] = vv[i] * rs * w[t * 8 + i];
  if (do_rope) {
    int s = row % SLEN;
    int f = s >> 8, hh = (s >> 4) & 15, ww = s & 15;
    int jb = ((t * 8) % HDIM) >> 1;
#pragma unroll
    for (int p = 0; p < 4; ++p) {
      int j = jb + p;
      int src = (j < 22) ? f : ((j < 43) ? hh : ww);
      float c = fcos[src * 64 + j];
      float sn = fsin[src * 64 + j];
      float xr_ = y[2 * p], xi = y[2 * p + 1];
      y[2 * p] = xr_ * c - xi * sn;
      y[2 * p + 1] = xr_ * sn + xi * c;
    }
  }
  short8_t o;
#pragma unroll
  for (int i = 0; i < 8; ++i) o[i] = f2bf(y[i]);
  *(short8_t*)((short*)out + (size_t)row * DIMX + t * 8) = o;
}

// C = A(bf16 or f32->bf16) @ W(f32->bf16) + bias, with epilogue modes.
// mode 0: outF = v; 1: outB = bf16(v); 2: outB = bf16(gelu(v));
// mode 3: outF = resid + v * (scale? scale[b*scstride+n] : 1)
__global__ __launch_bounds__(256) void gemm_kernel(
    const bf16* __restrict__ Ab, const float* __restrict__ Af,
    const float* __restrict__ W, const float* __restrict__ bias,
    float* __restrict__ outF, bf16* __restrict__ outB,
    const float* __restrict__ resid, const float* __restrict__ scale,
    int scstride, int rows_per_b, int M, int N, int K, int mode) {
  __shared__ short At[128 * 40];
  __shared__ short Wt[128 * 40];
  int t = threadIdx.x, lane = t & 63, wv = t >> 6;
  int m0 = blockIdx.y * 128, n0 = blockIdx.x * 128;
  f32x4 acc[4][4] = {};
  int arow = t >> 1, acol = (t & 1) * 16;
  int wrow = t >> 3, wcol = (t & 7) * 16;
  int mo_l = (wv >> 1) * 64, no_l = (wv & 1) * 64;
  for (int kk = 0; kk < K; kk += 32) {
    if (Ab) {
      const short* src = (const short*)Ab + (size_t)(m0 + arow) * K + kk + acol;
      short8_t x0 = *(const short8_t*)src;
      short8_t x1 = *(const short8_t*)(src + 8);
      *(short8_t*)&At[arow * 40 + acol] = x0;
      *(short8_t*)&At[arow * 40 + acol + 8] = x1;
    } else {
      const float* src = Af + (size_t)(m0 + arow) * K + kk + acol;
      float4 f0 = *(const float4*)(src);
      float4 f1 = *(const float4*)(src + 4);
      float4 f2 = *(const float4*)(src + 8);
      float4 f3 = *(const float4*)(src + 12);
      float fv[16] = {f0.x,f0.y,f0.z,f0.w,f1.x,f1.y,f1.z,f1.w,
                      f2.x,f2.y,f2.z,f2.w,f3.x,f3.y,f3.z,f3.w};
      short8_t o0, o1;
#pragma unroll
      for (int j = 0; j < 8; ++j) { o0[j] = f2bf(fv[j]); o1[j] = f2bf(fv[8 + j]); }
      *(short8_t*)&At[arow * 40 + acol] = o0;
      *(short8_t*)&At[arow * 40 + acol + 8] = o1;
    }
    {
      const float* wsrc = W + (size_t)(kk + wrow) * N + n0 + wcol;
      float4 f0 = *(const float4*)(wsrc);
      float4 f1 = *(const float4*)(wsrc + 4);
      float4 f2 = *(const float4*)(wsrc + 8);
      float4 f3 = *(const float4*)(wsrc + 12);
      float fv[16] = {f0.x,f0.y,f0.z,f0.w,f1.x,f1.y,f1.z,f1.w,
                      f2.x,f2.y,f2.z,f2.w,f3.x,f3.y,f3.z,f3.w};
#pragma unroll
      for (int j = 0; j < 16; ++j) Wt[(wcol + j) * 40 + wrow] = f2bf(fv[j]);
    }
    __syncthreads();
    short8_t af[4], bfv[4];
#pragma unroll
    for (int mt = 0; mt < 4; ++mt)
      af[mt] = *(const short8_t*)&At[(mo_l + mt * 16 + (lane & 15)) * 40 + (lane >> 4) * 8];
#pragma unroll
    for (int nt = 0; nt < 4; ++nt)
      bfv[nt] = *(const short8_t*)&Wt[(no_l + nt * 16 + (lane & 15)) * 40 + (lane >> 4) * 8];
#pragma unroll
    for (int mt = 0; mt < 4; ++mt)
#pragma unroll
      for (int nt = 0; nt < 4; ++nt)
        acc[mt][nt] = __builtin_amdgcn_mfma_f32_16x16x32_bf16(af[mt], bfv[nt], acc[mt][nt], 0, 0, 0);
    __syncthreads();
  }
  int mo = m0 + mo_l, no = n0 + no_l;
#pragma unroll
  for (int mt = 0; mt < 4; ++mt)
#pragma unroll
    for (int nt = 0; nt < 4; ++nt) {
      int n = no + nt * 16 + (lane & 15);
      float bia = bias[n];
#pragma unroll
      for (int r = 0; r < 4; ++r) {
        int m = mo + mt * 16 + (lane >> 4) * 4 + r;
        float vv = acc[mt][nt][r] + bia;
        size_t idx = (size_t)m * N + n;
        if (mode == 0) {
          outF[idx] = vv;
        } else if (mode == 1) {
          ((short*)outB)[idx] = f2bf(vv);
        } else if (mode == 2) {
          float g = 0.5f * vv * (1.f + tanhf(0.7978845608f * (vv + 0.044715f * vv * vv * vv)));
          ((short*)outB)[idx] = f2bf(g);
        } else {
          float sc = scale ? scale[(size_t)(m / rows_per_b) * scstride + n] : 1.0f;
          outF[idx] = resid[idx] + vv * sc;
        }
      }
    }
}

// Flash attention: q (B,QL,DIM) bf16, k/v (B,KVL,DIM) bf16, out y (B,QL,DIM) bf16
__global__ __launch_bounds__(256) void attn_kernel(
    const bf16* __restrict__ q, const bf16* __restrict__ k,
    const bf16* __restrict__ v, bf16* __restrict__ y,
    int QL, int KVL, float scl) {
  __shared__ short Kt[64 * 136];
  __shared__ short Vt[128 * 72];
  __shared__ short Pl[4 * 16 * 72];
  __shared__ float rl[4 * 16];
  __shared__ float ll[4 * 16];
  int t = threadIdx.x, lane = t & 63, wv = t >> 6;
  int bh = blockIdx.y;
  int b = bh / NHEADS, h = bh % NHEADS;
  int q0 = blockIdx.x * 64 + wv * 16;
  const short* qp = (const short*)q;
  const short* kp = (const short*)k;
  const short* vp = (const short*)v;
  short8_t qf[4];
  {
    size_t qbase = ((size_t)(b * QL) + q0 + (lane & 15)) * DIMX + h * HDIM + (lane >> 4) * 8;
#pragma unroll
    for (int kc = 0; kc < 4; ++kc) qf[kc] = *(const short8_t*)(qp + qbase + kc * 32);
  }
  f32x4 o[8] = {};
  float m_run = -1e30f, l_run = 0.f;
  int strow = t >> 2, stcol = (t & 3) * 32;
  for (int kt0 = 0; kt0 < KVL; kt0 += 64) {
    const short* ks = kp + ((size_t)(b * KVL + kt0 + strow) * DIMX + h * HDIM + stcol);
    const short* vs = vp + ((size_t)(b * KVL + kt0 + strow) * DIMX + h * HDIM + stcol);
#pragma unroll
    for (int c = 0; c < 4; ++c)
      *(short8_t*)&Kt[strow * 136 + stcol + c * 8] = *(const short8_t*)(ks + c * 8);
#pragma unroll
    for (int c = 0; c < 4; ++c) {
      short8_t vvv = *(const short8_t*)(vs + c * 8);
#pragma unroll
      for (int e = 0; e < 8; ++e) Vt[(stcol + c * 8 + e) * 72 + strow] = vvv[e];
    }
    __syncthreads();
    f32x4 st[4];
#pragma unroll
    for (int kt = 0; kt < 4; ++kt) {
      f32x4 a = {0.f, 0.f, 0.f, 0.f};
#pragma unroll
      for (int kc = 0; kc < 4; ++kc) {
        short8_t kf = *(const short8_t*)&Kt[(kt * 16 + (lane & 15)) * 136 + kc * 32 + (lane >> 4) * 8];
        a = __builtin_amdgcn_mfma_f32_16x16x32_bf16(kf, qf[kc], a, 0, 0, 0);
      }
      st[kt] = a;
    }
    float mt_ = -1e30f;
#pragma unroll
    for (int kt = 0; kt < 4; ++kt)
#pragma unroll
      for (int r = 0; r < 4; ++r) mt_ = fmaxf(mt_, st[kt][r]);
    mt_ = fmaxf(mt_, __shfl_xor(mt_, 16, 64));
    mt_ = fmaxf(mt_, __shfl_xor(mt_, 32, 64));
    mt_ *= scl;
    float m_new = fmaxf(m_run, mt_);
    float rfac = __expf(m_run - m_new);
    float ps = 0.f;
#pragma unroll
    for (int kt = 0; kt < 4; ++kt)
#pragma unroll
      for (int r = 0; r < 4; ++r) {
        float p = __expf(st[kt][r] * scl - m_new);
        st[kt][r] = p;
        ps += p;
      }
    ps += __shfl_xor(ps, 16, 64);
    ps += __shfl_xor(ps, 32, 64);
    l_run = l_run * rfac + ps;
    m_run = m_new;
    if (lane < 16) rl[wv * 16 + lane] = rfac;
#pragma unroll
    for (int kt = 0; kt < 4; ++kt)
#pragma unroll
      for (int r = 0; r < 4; ++r)
        Pl[(wv * 16 + (lane & 15)) * 72 + kt * 16 + (lane >> 4) * 4 + r] = f2bf(st[kt][r]);
    float rr[4];
#pragma unroll
    for (int r = 0; r < 4; ++r) rr[r] = rl[wv * 16 + (lane >> 4) * 4 + r];
#pragma unroll
    for (int dt = 0; dt < 8; ++dt)
#pragma unroll
      for (int r = 0; r < 4; ++r) o[dt][r] *= rr[r];
#pragma unroll
    for (int kc2 = 0; kc2 < 2; ++kc2) {
      short8_t pa = *(const short8_t*)&Pl[(wv * 16 + (lane & 15)) * 72 + kc2 * 32 + (lane >> 4) * 8];
#pragma unroll
      for (int dt = 0; dt < 8; ++dt) {
        short8_t vf = *(const short8_t*)&Vt[(dt * 16 + (lane & 15)) * 72 + kc2 * 32 + (lane >> 4) * 8];
        o[dt] = __builtin_amdgcn_mfma_f32_16x16x32_bf16(pa, vf, o[dt], 0, 0, 0);
      }
    }
    __syncthreads();
  }
  if (lane < 16) ll[wv * 16 + lane] = 1.f / l_run;
  float li[4];
#pragma unroll
  for (int r = 0; r < 4; ++r) li[r] = ll[wv * 16 + (lane >> 4) * 4 + r];
  short* yp = (short*)y;
#pragma unroll
  for (int dt = 0; dt < 8; ++dt)
#pragma unroll
    for (int r = 0; r < 4; ++r) {
      int qq = q0 + (lane >> 4) * 4 + r;
      int d = dt * 16 + (lane & 15);
      yp[((size_t)(b * QL) + qq) * DIMX + h * HDIM + d] = f2bf(o[dt][r] * li[r]);
    }
}

// ws offsets (bytes)
#define OFF_X   0ull
#define OFF_EM  33554432ull
#define OFF_XN  33652736ull
#define OFF_Y   50429952ull
#define OFF_V   67207168ull
#define OFF_TMP 83984384ull
#define OFF_Q   117538816ull
#define OFF_K   134316032ull

extern "C" void kernel_launch(void* const* d_in, const int* in_sizes, int n_in,
                              void* d_out, int out_size, void* d_ws, size_t ws_size,
                              hipStream_t stream) {
  const float* x       = (const float*)d_in[0];
  const float* e       = (const float*)d_in[1];
  const float* context = (const float*)d_in[2];
  const float* fcos    = (const float*)d_in[3];
  const float* fsin    = (const float*)d_in[4];
  const float* modu    = (const float*)d_in[5];
  const float* sa_wq = (const float*)d_in[6];  const float* sa_bq = (const float*)d_in[7];
  const float* sa_wk = (const float*)d_in[8];  const float* sa_bk = (const float*)d_in[9];
  const float* sa_wv = (const float*)d_in[10]; const float* sa_bv = (const float*)d_in[11];
  const float* sa_wo = (const float*)d_in[12]; const float* sa_bo = (const float*)d_in[13];
  const float* sa_nq = (const float*)d_in[14]; const float* sa_nk = (const float*)d_in[15];
  const float* ca_wq = (const float*)d_in[16]; const float* ca_bq = (const float*)d_in[17];
  const float* ca_wk = (const float*)d_in[18]; const float* ca_bk = (const float*)d_in[19];
  const float* ca_wv = (const float*)d_in[20]; const float* ca_bv = (const float*)d_in[21];
  const float* ca_wo = (const float*)d_in[22]; const float* ca_bo = (const float*)d_in[23];
  const float* ca_nq = (const float*)d_in[24]; const float* ca_nk = (const float*)d_in[25];
  const float* n3_w  = (const float*)d_in[26]; const float* n3_b  = (const float*)d_in[27];
  const float* f_w1  = (const float*)d_in[28]; const float* f_b1  = (const float*)d_in[29];
  const float* f_w2  = (const float*)d_in[30]; const float* f_b2  = (const float*)d_in[31];

  char* ws = (char*)d_ws;
  float* xw  = (float*)(ws + OFF_X);
  float* em  = (float*)(ws + OFF_EM);
  bf16* xn   = (bf16*)(ws + OFF_XN);
  bf16* yb   = (bf16*)(ws + OFF_Y);
  bf16* vb   = (bf16*)(ws + OFF_V);
  float* tmp = (float*)(ws + OFF_TMP);
  bf16* qb   = (bf16*)(ws + OFF_Q);
  bf16* kb   = (bf16*)(ws + OFF_K);
  bf16* hb   = (bf16*)(ws + OFF_TMP);  // FFN hidden overlays tmp+q+k
  float* outF = (float*)d_out;

  const int M = BSZ * SLEN;        // 4096
  const int MC = BSZ * CTXL;       // 1024
  const float scl = 0.08838834764831845f;  // 1/sqrt(128)

  em_kernel<<<(BSZ * 6 * DIMX + 255) / 256, 256, 0, stream>>>(e, modu, em, BSZ * 6 * DIMX);

  // --- self attention ---
  ln_kernel<<<M, 256, 0, stream>>>(x, em + 1 * DIMX, em + 0 * DIMX, 6 * DIMX, 1.0f, SLEN, xn);

  gemm_kernel<<<dim3(16, 32), 256, 0, stream>>>(xn, nullptr, sa_wq, sa_bq, tmp, nullptr,
                                                nullptr, nullptr, 0, 1, M, DIMX, DIMX, 0);
  rms_rope_kernel<<<M, 256, 0, stream>>>(tmp, sa_nq, fcos, fsin, 1, qb);

  gemm_kernel<<<dim3(16, 32), 256, 0, stream>>>(xn, nullptr, sa_wk, sa_bk, tmp, nullptr,
                                                nullptr, nullptr, 0, 1, M, DIMX, DIMX, 0);
  rms_rope_kernel<<<M, 256, 0, stream>>>(tmp, sa_nk, fcos, fsin, 1, kb);

  gemm_kernel<<<dim3(16, 32), 256, 0, stream>>>(xn, nullptr, sa_wv, sa_bv, nullptr, vb,
                                                nullptr, nullptr, 0, 1, M, DIMX, DIMX, 1);

  attn_kernel<<<dim3(SLEN / 64, BSZ * NHEADS), 256, 0, stream>>>(qb, kb, vb, yb, SLEN, SLEN, scl);

  gemm_kernel<<<dim3(16, 32), 256, 0, stream>>>(yb, nullptr, sa_wo, sa_bo, xw, nullptr,
                                                x, em + 2 * DIMX, 6 * DIMX, SLEN, M, DIMX, DIMX, 3);

  // --- cross attention ---
  ln_kernel<<<M, 256, 0, stream>>>(xw, n3_w, n3_b, 0, 0.0f, SLEN, xn);

  gemm_kernel<<<dim3(16, 32), 256, 0, stream>>>(xn, nullptr, ca_wq, ca_bq, tmp, nullptr,
                                                nullptr, nullptr, 0, 1, M, DIMX, DIMX, 0);
  rms_rope_kernel<<<M, 256, 0, stream>>>(tmp, ca_nq, fcos, fsin, 0, qb);

  gemm_kernel<<<dim3(16, 8), 256, 0, stream>>>(nullptr, context, ca_wk, ca_bk, tmp, nullptr,
                                               nullptr, nullptr, 0, 1, MC, DIMX, DIMX, 0);
  rms_rope_kernel<<<MC, 256, 0, stream>>>(tmp, ca_nk, fcos, fsin, 0, kb);

  gemm_kernel<<<dim3(16, 8), 256, 0, stream>>>(nullptr, context, ca_wv, ca_bv, nullptr, vb,
                                               nullptr, nullptr, 0, 1, MC, DIMX, DIMX, 1);

  attn_kernel<<<dim3(SLEN / 64, BSZ * NHEADS), 256, 0, stream>>>(qb, kb, vb, yb, SLEN, CTXL, scl);

  gemm_kernel<<<dim3(16, 32), 256, 0, stream>>>(yb, nullptr, ca_wo, ca_bo, xw, nullptr,
                                                xw, nullptr, 0, 1, M, DIMX, DIMX, 3);

  // --- FFN ---
  ln_kernel<<<M, 256, 0, stream>>>(xw, em + 4 * DIMX, em + 3 * DIMX, 6 * DIMX, 1.0f, SLEN, xn);

  gemm_kernel<<<dim3(64, 32), 256, 0, stream>>>(xn, nullptr, f_w1, f_b1, nullptr, hb,
                                                nullptr, nullptr, 0, 1, M, FFND, DIMX, 2);

  gemm_kernel<<<dim3(16, 32), 256, 0, stream>>>(hb, nullptr, f_w2, f_b2, outF, nullptr,
                                                xw, em + 5 * DIMX, 6 * DIMX, SLEN, M, DIMX, FFND, 3);
}

// Round 2
// 1304.295 us; speedup vs baseline: 1.5600x; 1.5600x over previous
//
#include <hip/hip_runtime.h>
#include <hip/hip_bf16.h>
#include <math.h>

#define DIMX 2048
#define SLEN 2048
#define BSZ 2
#define NHEADS 16
#define HDIM 128
#define FFND 8192
#define CTXL 512
#define LN_EPS 1e-6f

typedef __attribute__((ext_vector_type(8))) short short8_t;
typedef __attribute__((ext_vector_type(4))) short short4_t;
typedef __attribute__((ext_vector_type(4))) float f32x4;
typedef __hip_bfloat16 bf16;

__device__ __forceinline__ short f2bf(float f) {
  union { float f; unsigned u; } v; v.f = f;
  return (short)((v.u + 0x7FFFu + ((v.u >> 16) & 1u)) >> 16);
}
__device__ __forceinline__ float bf2f(short s) {
  union { unsigned u; float f; } v; v.u = ((unsigned)(unsigned short)s) << 16;
  return v.f;
}

__device__ __forceinline__ void gload16(const void* g, void* l) {
  __builtin_amdgcn_global_load_lds(
      (const __attribute__((address_space(1))) unsigned int*)g,
      (__attribute__((address_space(3))) unsigned int*)l, 16, 0, 0);
}

__device__ __forceinline__ float wred_sum(float v) {
#pragma unroll
  for (int o = 32; o > 0; o >>= 1) v += __shfl_xor(v, o, 64);
  return v;
}

// em = modulation(1,6,D) + e(B,6,D)
__global__ void em_kernel(const float* __restrict__ e, const float* __restrict__ mod,
                          float* __restrict__ em, int n) {
  int i = blockIdx.x * 256 + threadIdx.x;
  if (i < n) em[i] = e[i] + mod[i % (6 * DIMX)];
}

// fp32 -> bf16 elementwise (8/thread)
__global__ void cvt_kernel(const float* __restrict__ in, bf16* __restrict__ out, int n8) {
  int i = blockIdx.x * 256 + threadIdx.x;
  if (i >= n8) return;
  float4 a = *(const float4*)(in + (size_t)i * 8);
  float4 b = *(const float4*)(in + (size_t)i * 8 + 4);
  float fv[8] = {a.x, a.y, a.z, a.w, b.x, b.y, b.z, b.w};
  short8_t o;
#pragma unroll
  for (int j = 0; j < 8; ++j) o[j] = f2bf(fv[j]);
  *(short8_t*)((short*)out + (size_t)i * 8) = o;
}

// W fp32 [K][N] -> Wt bf16 [N][K], 64x64 tiles
__global__ __launch_bounds__(256) void transpose_w(const float* __restrict__ W,
                                                   bf16* __restrict__ Wt, int K, int N) {
  __shared__ short tile[64 * 68];
  int k0 = blockIdx.y << 6, n0 = blockIdx.x << 6;
  int t = threadIdx.x;
#pragma unroll
  for (int p = 0; p < 4; ++p) {
    int lin = p * 1024 + t * 4;
    int kr = lin >> 6, nc = lin & 63;
    float4 f = *(const float4*)(W + (size_t)(k0 + kr) * N + n0 + nc);
    tile[(nc + 0) * 68 + kr] = f2bf(f.x);
    tile[(nc + 1) * 68 + kr] = f2bf(f.y);
    tile[(nc + 2) * 68 + kr] = f2bf(f.z);
    tile[(nc + 3) * 68 + kr] = f2bf(f.w);
  }
  __syncthreads();
#pragma unroll
  for (int p = 0; p < 4; ++p) {
    int lin = p * 1024 + t * 4;
    int nr = lin >> 6, kc = lin & 63;
    short4_t s = *(const short4_t*)&tile[nr * 68 + kc];
    *(short4_t*)((short*)Wt + (size_t)(n0 + nr) * K + k0 + kc) = s;
  }
}

// LayerNorm (no affine) then y*g + b;  g = addone + gamma[b*gbstride + d]
__global__ __launch_bounds__(256) void ln_kernel(
    const float* __restrict__ x, const float* __restrict__ gamma,
    const float* __restrict__ beta, int gbstride, float addone,
    int rows_per_b, bf16* __restrict__ out) {
  int row = blockIdx.x;
  int t = threadIdx.x;
  const float* xr = x + (size_t)row * DIMX;
  float4 v0 = *(const float4*)(xr + t * 8);
  float4 v1 = *(const float4*)(xr + t * 8 + 4);
  float vv[8] = {v0.x, v0.y, v0.z, v0.w, v1.x, v1.y, v1.z, v1.w};
  float s = 0.f, ss = 0.f;
#pragma unroll
  for (int i = 0; i < 8; ++i) { s += vv[i]; ss += vv[i] * vv[i]; }
  __shared__ float red[8];
  s = wred_sum(s); ss = wred_sum(ss);
  int wid = t >> 6;
  if ((t & 63) == 0) { red[wid] = s; red[4 + wid] = ss; }
  __syncthreads();
  float sum = red[0] + red[1] + red[2] + red[3];
  float sumsq = red[4] + red[5] + red[6] + red[7];
  float mean = sum * (1.f / DIMX);
  float var = sumsq * (1.f / DIMX) - mean * mean;
  float rs = rsqrtf(var + LN_EPS);
  int b = row / rows_per_b;
  const float* g = gamma + (size_t)b * gbstride;
  const float* be = beta + (size_t)b * gbstride;
  short8_t o;
#pragma unroll
  for (int i = 0; i < 8; ++i) {
    int d = t * 8 + i;
    float y = (vv[i] - mean) * rs;
    o[i] = f2bf(y * (addone + g[d]) + be[d]);
  }
  *(short8_t*)((short*)out + (size_t)row * DIMX + t * 8) = o;
}

// RMSNorm over DIM (bf16 in), * w, optional RoPE, out bf16
__global__ __launch_bounds__(256) void rms_rope_kernel(
    const bf16* __restrict__ x, const float* __restrict__ w,
    const float* __restrict__ fcos, const float* __restrict__ fsin,
    int do_rope, bf16* __restrict__ out) {
  int row = blockIdx.x;
  int t = threadIdx.x;
  short8_t xi = *(const short8_t*)((const short*)x + (size_t)row * DIMX + t * 8);
  float vv[8];
#pragma unroll
  for (int i = 0; i < 8; ++i) vv[i] = bf2f(xi[i]);
  float ss = 0.f;
#pragma unroll
  for (int i = 0; i < 8; ++i) ss += vv[i] * vv[i];
  __shared__ float red[4];
  ss = wred_sum(ss);
  int wid = t >> 6;
  if ((t & 63) == 0) red[wid] = ss;
  __syncthreads();
  float sumsq = red[0] + red[1] + red[2] + red[3];
  float rs = rsqrtf(sumsq * (1.f / DIMX) + LN_EPS);
  float y[8];
#pragma unroll
  for (int i = 0; i < 8; ++i) y[i] = vv[i] * rs * w[t * 8 + i];
  if (do_rope) {
    int s = row % SLEN;
    int f = s >> 8, hh = (s >> 4) & 15, ww = s & 15;
    int jb = ((t * 8) % HDIM) >> 1;
#pragma unroll
    for (int p = 0; p < 4; ++p) {
      int j = jb + p;
      int src = (j < 22) ? f : ((j < 43) ? hh : ww);
      float c = fcos[src * 64 + j];
      float sn = fsin[src * 64 + j];
      float xr_ = y[2 * p], xim = y[2 * p + 1];
      y[2 * p] = xr_ * c - xim * sn;
      y[2 * p + 1] = xr_ * sn + xim * c;
    }
  }
  short8_t o;
#pragma unroll
  for (int i = 0; i < 8; ++i) o[i] = f2bf(y[i]);
  *(short8_t*)((short*)out + (size_t)row * DIMX + t * 8) = o;
}

// C[M][N] = A[M][K](bf16) @ Bt[N][K](bf16)^T + bias. m97-style: global_load_lds
// staging w/ chunk-XOR swizzle, 128x128 tile, 4 waves, 16x16x32 MFMA.
// mode 1: outB = bf16(v); 2: outB = bf16(gelu(v)); 3: outF = resid + v*scale
__global__ __launch_bounds__(256) void gemm_bt(
    const bf16* __restrict__ A, const bf16* __restrict__ Bt,
    const float* __restrict__ bias,
    float* outF, bf16* outB,
    const float* resid, const float* __restrict__ scale,
    int scstride, int rows_per_b, int gn, int N, int K, int mode) {
  __shared__ short As[128 * 32];
  __shared__ short Bs[128 * 32];
  int t = threadIdx.x, lane = t & 63, wv = t >> 6;
  // bijective XCD swizzle (grids here are always %8==0)
  int nwg = gridDim.x;
  int cpx = nwg >> 3;
  int swz = (blockIdx.x & 7) * cpx + (blockIdx.x >> 3);
  int by = swz / gn, bx = swz % gn;
  int m0 = by << 7, n0 = bx << 7;
  f32x4 acc[4][4] = {};
  int mo_l = (wv >> 1) << 6, no_l = (wv & 1) << 6;

  // staging geometry: slot = issue*256 + t; r = slot>>2 (row), c = slot&3 (16B chunk)
  int rS = t >> 2;
  int cS = ((t & 3) ^ ((rS ^ (rS >> 2)) & 3)) << 3;  // pre-swizzled source chunk
  const short* Ap = (const short*)A;
  const short* Bp = (const short*)Bt;
  size_t arow0 = (size_t)(m0 + rS) * K + cS;
  size_t arow1 = (size_t)(m0 + 64 + rS) * K + cS;
  size_t brow0 = (size_t)(n0 + rS) * K + cS;
  size_t brow1 = (size_t)(n0 + 64 + rS) * K + cS;
  short* ldsA0 = &As[(wv * 64) * 8];
  short* ldsA1 = &As[(256 + wv * 64) * 8];
  short* ldsB0 = &Bs[(wv * 64) * 8];
  short* ldsB1 = &Bs[(256 + wv * 64) * 8];

  int koff = lane >> 4;
  int rowA[4], ccA[4], rowB[4], ccB[4];
#pragma unroll
  for (int i = 0; i < 4; ++i) {
    rowA[i] = mo_l + i * 16 + (lane & 15);
    ccA[i] = (koff ^ ((rowA[i] ^ (rowA[i] >> 2)) & 3)) << 3;
    rowB[i] = no_l + i * 16 + (lane & 15);
    ccB[i] = (koff ^ ((rowB[i] ^ (rowB[i] >> 2)) & 3)) << 3;
  }

  for (int kk = 0; kk < K; kk += 32) {
    gload16(Ap + arow0 + kk, ldsA0);
    gload16(Ap + arow1 + kk, ldsA1);
    gload16(Bp + brow0 + kk, ldsB0);
    gload16(Bp + brow1 + kk, ldsB1);
    __syncthreads();
    short8_t af[4], bfv[4];
#pragma unroll
    for (int mt = 0; mt < 4; ++mt)
      af[mt] = *(const short8_t*)&As[rowA[mt] * 32 + ccA[mt]];
#pragma unroll
    for (int nt = 0; nt < 4; ++nt)
      bfv[nt] = *(const short8_t*)&Bs[rowB[nt] * 32 + ccB[nt]];
#pragma unroll
    for (int mt = 0; mt < 4; ++mt)
#pragma unroll
      for (int nt = 0; nt < 4; ++nt)
        acc[mt][nt] = __builtin_amdgcn_mfma_f32_16x16x32_bf16(af[mt], bfv[nt], acc[mt][nt], 0, 0, 0);
    __syncthreads();
  }

  int mo = m0 + mo_l, no = n0 + no_l;
#pragma unroll
  for (int mt = 0; mt < 4; ++mt)
#pragma unroll
    for (int nt = 0; nt < 4; ++nt) {
      int n = no + nt * 16 + (lane & 15);
      float bia = bias[n];
#pragma unroll
      for (int r = 0; r < 4; ++r) {
        int m = mo + mt * 16 + (lane >> 4) * 4 + r;
        float vv = acc[mt][nt][r] + bia;
        size_t idx = (size_t)m * N + n;
        if (mode == 1) {
          ((short*)outB)[idx] = f2bf(vv);
        } else if (mode == 2) {
          float g = 0.5f * vv * (1.f + tanhf(0.7978845608f * (vv + 0.044715f * vv * vv * vv)));
          ((short*)outB)[idx] = f2bf(g);
        } else {
          float sc = scale ? scale[(size_t)(m / rows_per_b) * scstride + n] : 1.0f;
          outF[idx] = resid[idx] + vv * sc;
        }
      }
    }
}

// Flash attention (unchanged from passing R1)
__global__ __launch_bounds__(256) void attn_kernel(
    const bf16* __restrict__ q, const bf16* __restrict__ k,
    const bf16* __restrict__ v, bf16* __restrict__ y,
    int QL, int KVL, float scl) {
  __shared__ short Kt[64 * 136];
  __shared__ short Vt[128 * 72];
  __shared__ short Pl[4 * 16 * 72];
  __shared__ float rl[4 * 16];
  __shared__ float ll[4 * 16];
  int t = threadIdx.x, lane = t & 63, wv = t >> 6;
  int bh = blockIdx.y;
  int b = bh / NHEADS, h = bh % NHEADS;
  int q0 = blockIdx.x * 64 + wv * 16;
  const short* qp = (const short*)q;
  const short* kp = (const short*)k;
  const short* vp = (const short*)v;
  short8_t qf[4];
  {
    size_t qbase = ((size_t)(b * QL) + q0 + (lane & 15)) * DIMX + h * HDIM + (lane >> 4) * 8;
#pragma unroll
    for (int kc = 0; kc < 4; ++kc) qf[kc] = *(const short8_t*)(qp + qbase + kc * 32);
  }
  f32x4 o[8] = {};
  float m_run = -1e30f, l_run = 0.f;
  int strow = t >> 2, stcol = (t & 3) * 32;
  for (int kt0 = 0; kt0 < KVL; kt0 += 64) {
    const short* ks = kp + ((size_t)(b * KVL + kt0 + strow) * DIMX + h * HDIM + stcol);
    const short* vs = vp + ((size_t)(b * KVL + kt0 + strow) * DIMX + h * HDIM + stcol);
#pragma unroll
    for (int c = 0; c < 4; ++c)
      *(short8_t*)&Kt[strow * 136 + stcol + c * 8] = *(const short8_t*)(ks + c * 8);
#pragma unroll
    for (int c = 0; c < 4; ++c) {
      short8_t vvv = *(const short8_t*)(vs + c * 8);
#pragma unroll
      for (int e = 0; e < 8; ++e) Vt[(stcol + c * 8 + e) * 72 + strow] = vvv[e];
    }
    __syncthreads();
    f32x4 st[4];
#pragma unroll
    for (int kt = 0; kt < 4; ++kt) {
      f32x4 a = {0.f, 0.f, 0.f, 0.f};
#pragma unroll
      for (int kc = 0; kc < 4; ++kc) {
        short8_t kf = *(const short8_t*)&Kt[(kt * 16 + (lane & 15)) * 136 + kc * 32 + (lane >> 4) * 8];
        a = __builtin_amdgcn_mfma_f32_16x16x32_bf16(kf, qf[kc], a, 0, 0, 0);
      }
      st[kt] = a;
    }
    float mt_ = -1e30f;
#pragma unroll
    for (int kt = 0; kt < 4; ++kt)
#pragma unroll
      for (int r = 0; r < 4; ++r) mt_ = fmaxf(mt_, st[kt][r]);
    mt_ = fmaxf(mt_, __shfl_xor(mt_, 16, 64));
    mt_ = fmaxf(mt_, __shfl_xor(mt_, 32, 64));
    mt_ *= scl;
    float m_new = fmaxf(m_run, mt_);
    float rfac = __expf(m_run - m_new);
    float ps = 0.f;
#pragma unroll
    for (int kt = 0; kt < 4; ++kt)
#pragma unroll
      for (int r = 0; r < 4; ++r) {
        float p = __expf(st[kt][r] * scl - m_new);
        st[kt][r] = p;
        ps += p;
      }
    ps += __shfl_xor(ps, 16, 64);
    ps += __shfl_xor(ps, 32, 64);
    l_run = l_run * rfac + ps;
    m_run = m_new;
    if (lane < 16) rl[wv * 16 + lane] = rfac;
#pragma unroll
    for (int kt = 0; kt < 4; ++kt)
#pragma unroll
      for (int r = 0; r < 4; ++r)
        Pl[(wv * 16 + (lane & 15)) * 72 + kt * 16 + (lane >> 4) * 4 + r] = f2bf(st[kt][r]);
    float rr[4];
#pragma unroll
    for (int r = 0; r < 4; ++r) rr[r] = rl[wv * 16 + (lane >> 4) * 4 + r];
#pragma unroll
    for (int dt = 0; dt < 8; ++dt)
#pragma unroll
      for (int r = 0; r < 4; ++r) o[dt][r] *= rr[r];
#pragma unroll
    for (int kc2 = 0; kc2 < 2; ++kc2) {
      short8_t pa = *(const short8_t*)&Pl[(wv * 16 + (lane & 15)) * 72 + kc2 * 32 + (lane >> 4) * 8];
#pragma unroll
      for (int dt = 0; dt < 8; ++dt) {
        short8_t vf = *(const short8_t*)&Vt[(dt * 16 + (lane & 15)) * 72 + kc2 * 32 + (lane >> 4) * 8];
        o[dt] = __builtin_amdgcn_mfma_f32_16x16x32_bf16(pa, vf, o[dt], 0, 0, 0);
      }
    }
    __syncthreads();
  }
  if (lane < 16) ll[wv * 16 + lane] = 1.f / l_run;
  float li[4];
#pragma unroll
  for (int r = 0; r < 4; ++r) li[r] = ll[wv * 16 + (lane >> 4) * 4 + r];
  short* yp = (short*)y;
#pragma unroll
  for (int dt = 0; dt < 8; ++dt)
#pragma unroll
    for (int r = 0; r < 4; ++r) {
      int qq = q0 + (lane >> 4) * 4 + r;
      int d = dt * 16 + (lane & 15);
      yp[((size_t)(b * QL) + qq) * DIMX + h * HDIM + d] = f2bf(o[dt][r] * li[r]);
    }
}

// ws layout (bytes)
#define OFF_EM   0ull
#define OFF_XN   (1ull << 20)
#define OFF_TMPB (17ull << 20)
#define OFF_QB   (33ull << 20)
#define OFF_KB   (49ull << 20)
#define OFF_VB   (65ull << 20)
#define OFF_YB   (81ull << 20)
#define OFF_HB   OFF_QB            // 33..97 MB overlays qb/kb/vb/yb (dead by FFN)
#define OFF_CTX  (97ull << 20)
#define OFF_WBUF (101ull << 20)    // 32 MB max (FFN weight)

extern "C" void kernel_launch(void* const* d_in, const int* in_sizes, int n_in,
                              void* d_out, int out_size, void* d_ws, size_t ws_size,
                              hipStream_t stream) {
  const float* x       = (const float*)d_in[0];
  const float* e       = (const float*)d_in[1];
  const float* context = (const float*)d_in[2];
  const float* fcos    = (const float*)d_in[3];
  const float* fsin    = (const float*)d_in[4];
  const float* modu    = (const float*)d_in[5];
  const float* sa_wq = (const float*)d_in[6];  const float* sa_bq = (const float*)d_in[7];
  const float* sa_wk = (const float*)d_in[8];  const float* sa_bk = (const float*)d_in[9];
  const float* sa_wv = (const float*)d_in[10]; const float* sa_bv = (const float*)d_in[11];
  const float* sa_wo = (const float*)d_in[12]; const float* sa_bo = (const float*)d_in[13];
  const float* sa_nq = (const float*)d_in[14]; const float* sa_nk = (const float*)d_in[15];
  const float* ca_wq = (const float*)d_in[16]; const float* ca_bq = (const float*)d_in[17];
  const float* ca_wk = (const float*)d_in[18]; const float* ca_bk = (const float*)d_in[19];
  const float* ca_wv = (const float*)d_in[20]; const float* ca_bv = (const float*)d_in[21];
  const float* ca_wo = (const float*)d_in[22]; const float* ca_bo = (const float*)d_in[23];
  const float* ca_nq = (const float*)d_in[24]; const float* ca_nk = (const float*)d_in[25];
  const float* n3_w  = (const float*)d_in[26]; const float* n3_b  = (const float*)d_in[27];
  const float* f_w1  = (const float*)d_in[28]; const float* f_b1  = (const float*)d_in[29];
  const float* f_w2  = (const float*)d_in[30]; const float* f_b2  = (const float*)d_in[31];

  char* ws = (char*)d_ws;
  float* em  = (float*)(ws + OFF_EM);
  bf16* xn   = (bf16*)(ws + OFF_XN);
  bf16* tmpb = (bf16*)(ws + OFF_TMPB);
  bf16* qb   = (bf16*)(ws + OFF_QB);
  bf16* kb   = (bf16*)(ws + OFF_KB);
  bf16* vb   = (bf16*)(ws + OFF_VB);
  bf16* yb   = (bf16*)(ws + OFF_YB);
  bf16* hb   = (bf16*)(ws + OFF_HB);
  bf16* ctxb = (bf16*)(ws + OFF_CTX);
  bf16* wbuf = (bf16*)(ws + OFF_WBUF);
  float* xw  = (float*)d_out;   // residual stream lives in d_out

  const int M = BSZ * SLEN;   // 4096
  const int MC = BSZ * CTXL;  // 1024
  const float scl = 0.08838834764831845f;

#define TRANS(W, Kd, Nd) transpose_w<<<dim3((Nd) / 64, (Kd) / 64), 256, 0, stream>>>(W, wbuf, Kd, Nd)
#define GEMM(Am, Md, Nd, Kd, bias, oF, oB, res, sc, scs, rpb, mode) \
  gemm_bt<<<((Md) / 128) * ((Nd) / 128), 256, 0, stream>>>(Am, wbuf, bias, oF, oB, res, sc, scs, rpb, (Nd) / 128, Nd, Kd, mode)

  em_kernel<<<(BSZ * 6 * DIMX + 255) / 256, 256, 0, stream>>>(e, modu, em, BSZ * 6 * DIMX);
  cvt_kernel<<<(MC * DIMX / 8 + 255) / 256, 256, 0, stream>>>(context, ctxb, MC * DIMX / 8);

  // --- self attention ---
  ln_kernel<<<M, 256, 0, stream>>>(x, em + 1 * DIMX, em + 0 * DIMX, 6 * DIMX, 1.0f, SLEN, xn);

  TRANS(sa_wq, DIMX, DIMX);
  GEMM(xn, M, DIMX, DIMX, sa_bq, nullptr, tmpb, nullptr, nullptr, 0, 1, 1);
  rms_rope_kernel<<<M, 256, 0, stream>>>(tmpb, sa_nq, fcos, fsin, 1, qb);

  TRANS(sa_wk, DIMX, DIMX);
  GEMM(xn, M, DIMX, DIMX, sa_bk, nullptr, tmpb, nullptr, nullptr, 0, 1, 1);
  rms_rope_kernel<<<M, 256, 0, stream>>>(tmpb, sa_nk, fcos, fsin, 1, kb);

  TRANS(sa_wv, DIMX, DIMX);
  GEMM(xn, M, DIMX, DIMX, sa_bv, nullptr, vb, nullptr, nullptr, 0, 1, 1);

  attn_kernel<<<dim3(SLEN / 64, BSZ * NHEADS), 256, 0, stream>>>(qb, kb, vb, yb, SLEN, SLEN, scl);

  TRANS(sa_wo, DIMX, DIMX);
  GEMM(yb, M, DIMX, DIMX, sa_bo, xw, nullptr, x, em + 2 * DIMX, 6 * DIMX, SLEN, 3);

  // --- cross attention ---
  ln_kernel<<<M, 256, 0, stream>>>(xw, n3_w, n3_b, 0, 0.0f, SLEN, xn);

  TRANS(ca_wq, DIMX, DIMX);
  GEMM(xn, M, DIMX, DIMX, ca_bq, nullptr, tmpb, nullptr, nullptr, 0, 1, 1);
  rms_rope_kernel<<<M, 256, 0, stream>>>(tmpb, ca_nq, fcos, fsin, 0, qb);

  TRANS(ca_wk, DIMX, DIMX);
  GEMM(ctxb, MC, DIMX, DIMX, ca_bk, nullptr, tmpb, nullptr, nullptr, 0, 1, 1);
  rms_rope_kernel<<<MC, 256, 0, stream>>>(tmpb, ca_nk, fcos, fsin, 0, kb);

  TRANS(ca_wv, DIMX, DIMX);
  GEMM(ctxb, MC, DIMX, DIMX, ca_bv, nullptr, vb, nullptr, nullptr, 0, 1, 1);

  attn_kernel<<<dim3(SLEN / 64, BSZ * NHEADS), 256, 0, stream>>>(qb, kb, vb, yb, SLEN, CTXL, scl);

  TRANS(ca_wo, DIMX, DIMX);
  GEMM(yb, M, DIMX, DIMX, ca_bo, xw, nullptr, xw, nullptr, 0, SLEN, 3);

  // --- FFN ---
  ln_kernel<<<M, 256, 0, stream>>>(xw, em + 4 * DIMX, em + 3 * DIMX, 6 * DIMX, 1.0f, SLEN, xn);

  TRANS(f_w1, DIMX, FFND);
  GEMM(xn, M, FFND, DIMX, f_b1, nullptr, hb, nullptr, nullptr, 0, 1, 2);

  TRANS(f_w2, FFND, DIMX);
  GEMM(hb, M, DIMX, FFND, f_b2, xw, nullptr, xw, em + 5 * DIMX, 6 * DIMX, SLEN, 3);
}

// Round 3
// 1119.930 us; speedup vs baseline: 1.8168x; 1.1646x over previous
//
#include <hip/hip_runtime.h>
#include <hip/hip_bf16.h>
#include <math.h>

#define DIMX 2048
#define SLEN 2048
#define BSZ 2
#define NHEADS 16
#define HDIM 128
#define FFND 8192
#define CTXL 512
#define LN_EPS 1e-6f

typedef __attribute__((ext_vector_type(8))) short short8_t;
typedef __attribute__((ext_vector_type(4))) short short4_t;
typedef __attribute__((ext_vector_type(4))) float f32x4;
typedef __hip_bfloat16 bf16;

__device__ __forceinline__ short f2bf(float f) {
  union { float f; unsigned u; } v; v.f = f;
  return (short)((v.u + 0x7FFFu + ((v.u >> 16) & 1u)) >> 16);
}
__device__ __forceinline__ float bf2f(short s) {
  union { unsigned u; float f; } v; v.u = ((unsigned)(unsigned short)s) << 16;
  return v.f;
}

__device__ __forceinline__ void gload16(const void* g, void* l) {
  __builtin_amdgcn_global_load_lds(
      (const __attribute__((address_space(1))) unsigned int*)g,
      (__attribute__((address_space(3))) unsigned int*)l, 16, 0, 0);
}

__device__ __forceinline__ float wred_sum(float v) {
#pragma unroll
  for (int o = 32; o > 0; o >>= 1) v += __shfl_xor(v, o, 64);
  return v;
}

__global__ void em_kernel(const float* __restrict__ e, const float* __restrict__ mod,
                          float* __restrict__ em, int n) {
  int i = blockIdx.x * 256 + threadIdx.x;
  if (i < n) em[i] = e[i] + mod[i % (6 * DIMX)];
}

__global__ void cvt_kernel(const float* __restrict__ in, bf16* __restrict__ out, int n8) {
  int i = blockIdx.x * 256 + threadIdx.x;
  if (i >= n8) return;
  float4 a = *(const float4*)(in + (size_t)i * 8);
  float4 b = *(const float4*)(in + (size_t)i * 8 + 4);
  float fv[8] = {a.x, a.y, a.z, a.w, b.x, b.y, b.z, b.w};
  short8_t o;
#pragma unroll
  for (int j = 0; j < 8; ++j) o[j] = f2bf(fv[j]);
  *(short8_t*)((short*)out + (size_t)i * 8) = o;
}

// pack up to 3 bias vectors of 2048 into one
__global__ void packb_kernel(const float* b0, const float* b1, const float* b2,
                             float* __restrict__ dst, int n) {
  int i = blockIdx.x * 256 + threadIdx.x;
  if (i >= n) return;
  int seg = i >> 11, j = i & 2047;
  const float* s = seg == 0 ? b0 : (seg == 1 ? b1 : b2);
  dst[i] = s[j];
}

// W fp32 [K][N] -> Wt bf16 [noff+N][K], 64x64 tiles
__global__ __launch_bounds__(256) void transpose_w(const float* __restrict__ W,
                                                   bf16* __restrict__ Wt, int K, int N,
                                                   int noff) {
  __shared__ short tile[64 * 68];
  int k0 = blockIdx.y << 6, n0 = blockIdx.x << 6;
  int t = threadIdx.x;
#pragma unroll
  for (int p = 0; p < 4; ++p) {
    int lin = p * 1024 + t * 4;
    int kr = lin >> 6, nc = lin & 63;
    float4 f = *(const float4*)(W + (size_t)(k0 + kr) * N + n0 + nc);
    tile[(nc + 0) * 68 + kr] = f2bf(f.x);
    tile[(nc + 1) * 68 + kr] = f2bf(f.y);
    tile[(nc + 2) * 68 + kr] = f2bf(f.z);
    tile[(nc + 3) * 68 + kr] = f2bf(f.w);
  }
  __syncthreads();
#pragma unroll
  for (int p = 0; p < 4; ++p) {
    int lin = p * 1024 + t * 4;
    int nr = lin >> 6, kc = lin & 63;
    short4_t s = *(const short4_t*)&tile[nr * 68 + kc];
    *(short4_t*)((short*)Wt + (size_t)(noff + n0 + nr) * K + k0 + kc) = s;
  }
}

__global__ __launch_bounds__(256) void ln_kernel(
    const float* __restrict__ x, const float* __restrict__ gamma,
    const float* __restrict__ beta, int gbstride, float addone,
    int rows_per_b, bf16* __restrict__ out) {
  int row = blockIdx.x;
  int t = threadIdx.x;
  const float* xr = x + (size_t)row * DIMX;
  float4 v0 = *(const float4*)(xr + t * 8);
  float4 v1 = *(const float4*)(xr + t * 8 + 4);
  float vv[8] = {v0.x, v0.y, v0.z, v0.w, v1.x, v1.y, v1.z, v1.w};
  float s = 0.f, ss = 0.f;
#pragma unroll
  for (int i = 0; i < 8; ++i) { s += vv[i]; ss += vv[i] * vv[i]; }
  __shared__ float red[8];
  s = wred_sum(s); ss = wred_sum(ss);
  int wid = t >> 6;
  if ((t & 63) == 0) { red[wid] = s; red[4 + wid] = ss; }
  __syncthreads();
  float sum = red[0] + red[1] + red[2] + red[3];
  float sumsq = red[4] + red[5] + red[6] + red[7];
  float mean = sum * (1.f / DIMX);
  float var = sumsq * (1.f / DIMX) - mean * mean;
  float rs = rsqrtf(var + LN_EPS);
  int b = row / rows_per_b;
  const float* g = gamma + (size_t)b * gbstride;
  const float* be = beta + (size_t)b * gbstride;
  short8_t o;
#pragma unroll
  for (int i = 0; i < 8; ++i) {
    int d = t * 8 + i;
    float y = (vv[i] - mean) * rs;
    o[i] = f2bf(y * (addone + g[d]) + be[d]);
  }
  *(short8_t*)((short*)out + (size_t)row * DIMX + t * 8) = o;
}

// RMSNorm over DIM (bf16 in, row stride xstride), * w, optional RoPE, out bf16 compact
__global__ __launch_bounds__(256) void rms_rope_kernel(
    const bf16* __restrict__ x, int xstride, const float* __restrict__ w,
    const float* __restrict__ fcos, const float* __restrict__ fsin,
    int do_rope, bf16* __restrict__ out) {
  int row = blockIdx.x;
  int t = threadIdx.x;
  short8_t xi = *(const short8_t*)((const short*)x + (size_t)row * xstride + t * 8);
  float vv[8];
#pragma unroll
  for (int i = 0; i < 8; ++i) vv[i] = bf2f(xi[i]);
  float ss = 0.f;
#pragma unroll
  for (int i = 0; i < 8; ++i) ss += vv[i] * vv[i];
  __shared__ float red[4];
  ss = wred_sum(ss);
  int wid = t >> 6;
  if ((t & 63) == 0) red[wid] = ss;
  __syncthreads();
  float sumsq = red[0] + red[1] + red[2] + red[3];
  float rs = rsqrtf(sumsq * (1.f / DIMX) + LN_EPS);
  float y[8];
#pragma unroll
  for (int i = 0; i < 8; ++i) y[i] = vv[i] * rs * w[t * 8 + i];
  if (do_rope) {
    int s = row % SLEN;
    int f = s >> 8, hh = (s >> 4) & 15, ww = s & 15;
    int jb = ((t * 8) % HDIM) >> 1;
#pragma unroll
    for (int p = 0; p < 4; ++p) {
      int j = jb + p;
      int src = (j < 22) ? f : ((j < 43) ? hh : ww);
      float c = fcos[src * 64 + j];
      float sn = fsin[src * 64 + j];
      float xr_ = y[2 * p], xim = y[2 * p + 1];
      y[2 * p] = xr_ * c - xim * sn;
      y[2 * p + 1] = xr_ * sn + xim * c;
    }
  }
  short8_t o;
#pragma unroll
  for (int i = 0; i < 8; ++i) o[i] = f2bf(y[i]);
  *(short8_t*)((short*)out + (size_t)row * DIMX + t * 8) = o;
}

// C[M][N] = A[M][K](bf16) @ Bt[N][K]^T + bias.  2-phase double-buffered pipeline,
// BK=64, chunk-XOR LDS swizzle both sides (rule #21), 128x128 tile, 4 waves.
// mode 1: outB = bf16(v); 2: outB = bf16(gelu(v)); 3: outF = resid + v*scale
__global__ __launch_bounds__(256) void gemm_bt(
    const bf16* __restrict__ A, const bf16* __restrict__ Bt,
    const float* __restrict__ bias,
    float* outF, bf16* outB,
    const float* resid, const float* __restrict__ scale,
    int scstride, int rows_per_b, int gn, int N, int K, int mode) {
  __shared__ short As[2][128 * 64];
  __shared__ short Bs[2][128 * 64];
  int t = threadIdx.x, lane = t & 63, wv = t >> 6;
  int nwg = gridDim.x, cpx = nwg >> 3;
  int swz = (blockIdx.x & 7) * cpx + (blockIdx.x >> 3);
  int by = swz / gn, bx = swz % gn;
  int m0 = by << 7, n0 = bx << 7;
  f32x4 acc[4][4] = {};
  int mo_l = (wv >> 1) << 6, no_l = (wv & 1) << 6;

  // staging: 4 issues each for A,B; issue j covers rows wv*32+j*8 .. +7
  int srow[4], scol[4];
#pragma unroll
  for (int j = 0; j < 4; ++j) {
    srow[j] = wv * 32 + j * 8 + (lane >> 3);
    scol[j] = ((lane & 7) ^ (srow[j] & 7)) << 3;  // pre-swizzled source chunk
  }
  const short* Ap = (const short*)A;
  const short* Bp = (const short*)Bt;

  int koff = lane >> 4;
  int rowA[4], rowB[4];
#pragma unroll
  for (int i = 0; i < 4; ++i) {
    rowA[i] = mo_l + i * 16 + (lane & 15);
    rowB[i] = no_l + i * 16 + (lane & 15);
  }

  auto stage = [&](int buf, int kk) {
#pragma unroll
    for (int j = 0; j < 4; ++j) {
      gload16(Ap + (size_t)(m0 + srow[j]) * K + kk + scol[j],
              &As[buf][(wv * 32 + j * 8) * 64]);
      gload16(Bp + (size_t)(n0 + srow[j]) * K + kk + scol[j],
              &Bs[buf][(wv * 32 + j * 8) * 64]);
    }
  };

  stage(0, 0);
  __syncthreads();
  int cur = 0;
  for (int kk = 0; kk < K; kk += 64) {
    int nxt = cur ^ 1;
    if (kk + 64 < K) stage(nxt, kk + 64);
    short8_t af[2][4], bfv[2][4];
#pragma unroll
    for (int h = 0; h < 2; ++h)
#pragma unroll
      for (int i = 0; i < 4; ++i) {
        int cA = ((h * 4 + koff) ^ (rowA[i] & 7)) << 3;
        af[h][i] = *(const short8_t*)&As[cur][rowA[i] * 64 + cA];
        int cB = ((h * 4 + koff) ^ (rowB[i] & 7)) << 3;
        bfv[h][i] = *(const short8_t*)&Bs[cur][rowB[i] * 64 + cB];
      }
#pragma unroll
    for (int h = 0; h < 2; ++h)
#pragma unroll
      for (int mt = 0; mt < 4; ++mt)
#pragma unroll
        for (int nt = 0; nt < 4; ++nt)
          acc[mt][nt] = __builtin_amdgcn_mfma_f32_16x16x32_bf16(af[h][mt], bfv[h][nt], acc[mt][nt], 0, 0, 0);
    __syncthreads();
    cur = nxt;
  }

  int mo = m0 + mo_l, no = n0 + no_l;
#pragma unroll
  for (int mt = 0; mt < 4; ++mt)
#pragma unroll
    for (int nt = 0; nt < 4; ++nt) {
      int n = no + nt * 16 + (lane & 15);
      float bia = bias[n];
#pragma unroll
      for (int r = 0; r < 4; ++r) {
        int m = mo + mt * 16 + (lane >> 4) * 4 + r;
        float vv = acc[mt][nt][r] + bia;
        size_t idx = (size_t)m * N + n;
        if (mode == 1) {
          ((short*)outB)[idx] = f2bf(vv);
        } else if (mode == 2) {
          float g = 0.5f * vv * (1.f + tanhf(0.7978845608f * (vv + 0.044715f * vv * vv * vv)));
          ((short*)outB)[idx] = f2bf(g);
        } else {
          float sc = scale ? scale[(size_t)(m / rows_per_b) * scstride + n] : 1.0f;
          outF[idx] = resid[idx] + vv * sc;
        }
      }
    }
}

// Flash attention with strided q/k/v inputs
__global__ __launch_bounds__(256) void attn_kernel(
    const bf16* __restrict__ q, const bf16* __restrict__ k,
    const bf16* __restrict__ v, bf16* __restrict__ y,
    int QL, int KVL, int qs, int ks, int vs, float scl) {
  __shared__ short Kt[64 * 136];
  __shared__ short Vt[128 * 72];
  __shared__ short Pl[4 * 16 * 72];
  __shared__ float rl[4 * 16];
  __shared__ float ll[4 * 16];
  int t = threadIdx.x, lane = t & 63, wv = t >> 6;
  int bh = blockIdx.y;
  int b = bh / NHEADS, h = bh % NHEADS;
  int q0 = blockIdx.x * 64 + wv * 16;
  const short* qp = (const short*)q;
  const short* kp = (const short*)k;
  const short* vp = (const short*)v;
  short8_t qf[4];
  {
    size_t qbase = ((size_t)(b * QL) + q0 + (lane & 15)) * qs + h * HDIM + (lane >> 4) * 8;
#pragma unroll
    for (int kc = 0; kc < 4; ++kc) qf[kc] = *(const short8_t*)(qp + qbase + kc * 32);
  }
  f32x4 o[8] = {};
  float m_run = -1e30f, l_run = 0.f;
  int strow = t >> 2, stcol = (t & 3) * 32;
  for (int kt0 = 0; kt0 < KVL; kt0 += 64) {
    const short* ksrc = kp + ((size_t)(b * KVL + kt0 + strow) * ks + h * HDIM + stcol);
    const short* vsrc = vp + ((size_t)(b * KVL + kt0 + strow) * vs + h * HDIM + stcol);
#pragma unroll
    for (int c = 0; c < 4; ++c)
      *(short8_t*)&Kt[strow * 136 + stcol + c * 8] = *(const short8_t*)(ksrc + c * 8);
#pragma unroll
    for (int c = 0; c < 4; ++c) {
      short8_t vvv = *(const short8_t*)(vsrc + c * 8);
#pragma unroll
      for (int e = 0; e < 8; ++e) Vt[(stcol + c * 8 + e) * 72 + strow] = vvv[e];
    }
    __syncthreads();
    f32x4 st[4];
#pragma unroll
    for (int kt = 0; kt < 4; ++kt) {
      f32x4 a = {0.f, 0.f, 0.f, 0.f};
#pragma unroll
      for (int kc = 0; kc < 4; ++kc) {
        short8_t kf = *(const short8_t*)&Kt[(kt * 16 + (lane & 15)) * 136 + kc * 32 + (lane >> 4) * 8];
        a = __builtin_amdgcn_mfma_f32_16x16x32_bf16(kf, qf[kc], a, 0, 0, 0);
      }
      st[kt] = a;
    }
    float mt_ = -1e30f;
#pragma unroll
    for (int kt = 0; kt < 4; ++kt)
#pragma unroll
      for (int r = 0; r < 4; ++r) mt_ = fmaxf(mt_, st[kt][r]);
    mt_ = fmaxf(mt_, __shfl_xor(mt_, 16, 64));
    mt_ = fmaxf(mt_, __shfl_xor(mt_, 32, 64));
    mt_ *= scl;
    float m_new = fmaxf(m_run, mt_);
    float rfac = __expf(m_run - m_new);
    float ps = 0.f;
#pragma unroll
    for (int kt = 0; kt < 4; ++kt)
#pragma unroll
      for (int r = 0; r < 4; ++r) {
        float p = __expf(st[kt][r] * scl - m_new);
        st[kt][r] = p;
        ps += p;
      }
    ps += __shfl_xor(ps, 16, 64);
    ps += __shfl_xor(ps, 32, 64);
    l_run = l_run * rfac + ps;
    m_run = m_new;
    if (lane < 16) rl[wv * 16 + lane] = rfac;
#pragma unroll
    for (int kt = 0; kt < 4; ++kt)
#pragma unroll
      for (int r = 0; r < 4; ++r)
        Pl[(wv * 16 + (lane & 15)) * 72 + kt * 16 + (lane >> 4) * 4 + r] = f2bf(st[kt][r]);
    float rr[4];
#pragma unroll
    for (int r = 0; r < 4; ++r) rr[r] = rl[wv * 16 + (lane >> 4) * 4 + r];
#pragma unroll
    for (int dt = 0; dt < 8; ++dt)
#pragma unroll
      for (int r = 0; r < 4; ++r) o[dt][r] *= rr[r];
#pragma unroll
    for (int kc2 = 0; kc2 < 2; ++kc2) {
      short8_t pa = *(const short8_t*)&Pl[(wv * 16 + (lane & 15)) * 72 + kc2 * 32 + (lane >> 4) * 8];
#pragma unroll
      for (int dt = 0; dt < 8; ++dt) {
        short8_t vf = *(const short8_t*)&Vt[(dt * 16 + (lane & 15)) * 72 + kc2 * 32 + (lane >> 4) * 8];
        o[dt] = __builtin_amdgcn_mfma_f32_16x16x32_bf16(pa, vf, o[dt], 0, 0, 0);
      }
    }
    __syncthreads();
  }
  if (lane < 16) ll[wv * 16 + lane] = 1.f / l_run;
  float li[4];
#pragma unroll
  for (int r = 0; r < 4; ++r) li[r] = ll[wv * 16 + (lane >> 4) * 4 + r];
  short* yp = (short*)y;
#pragma unroll
  for (int dt = 0; dt < 8; ++dt)
#pragma unroll
    for (int r = 0; r < 4; ++r) {
      int qq = q0 + (lane >> 4) * 4 + r;
      int d = dt * 16 + (lane & 15);
      yp[((size_t)(b * QL) + qq) * DIMX + h * HDIM + d] = f2bf(o[dt][r] * li[r]);
    }
}

// ws layout (bytes)
#define OFF_EM    0ull
#define OFF_BQKV  (512ull << 10)
#define OFF_BCKV  (560ull << 10)
#define OFF_XN    (1ull << 20)
#define OFF_QKV   (17ull << 20)   // fused qkv out: 48 MB (ends 65)
#define OFF_CAQ   (17ull << 20)   // cross-attn q out (16 MB), reuses qkv region
#define OFF_KV    (33ull << 20)   // cross-attn kv out (8 MB)
#define OFF_QB    (65ull << 20)
#define OFF_KB    (81ull << 20)
#define OFF_YB    (97ull << 20)
#define OFF_CTX   (113ull << 20)
#define OFF_WBUF  (117ull << 20)  // 32 MB max
#define OFF_HB    (17ull << 20)   // FFN hidden 64 MB (17..81), overlays qkv/caq/kv/qb

extern "C" void kernel_launch(void* const* d_in, const int* in_sizes, int n_in,
                              void* d_out, int out_size, void* d_ws, size_t ws_size,
                              hipStream_t stream) {
  const float* x       = (const float*)d_in[0];
  const float* e       = (const float*)d_in[1];
  const float* context = (const float*)d_in[2];
  const float* fcos    = (const float*)d_in[3];
  const float* fsin    = (const float*)d_in[4];
  const float* modu    = (const float*)d_in[5];
  const float* sa_wq = (const float*)d_in[6];  const float* sa_bq = (const float*)d_in[7];
  const float* sa_wk = (const float*)d_in[8];  const float* sa_bk = (const float*)d_in[9];
  const float* sa_wv = (const float*)d_in[10]; const float* sa_bv = (const float*)d_in[11];
  const float* sa_wo = (const float*)d_in[12]; const float* sa_bo = (const float*)d_in[13];
  const float* sa_nq = (const float*)d_in[14]; const float* sa_nk = (const float*)d_in[15];
  const float* ca_wq = (const float*)d_in[16]; const float* ca_bq = (const float*)d_in[17];
  const float* ca_wk = (const float*)d_in[18]; const float* ca_bk = (const float*)d_in[19];
  const float* ca_wv = (const float*)d_in[20]; const float* ca_bv = (const float*)d_in[21];
  const float* ca_wo = (const float*)d_in[22]; const float* ca_bo = (const float*)d_in[23];
  const float* ca_nq = (const float*)d_in[24]; const float* ca_nk = (const float*)d_in[25];
  const float* n3_w  = (const float*)d_in[26]; const float* n3_b  = (const float*)d_in[27];
  const float* f_w1  = (const float*)d_in[28]; const float* f_b1  = (const float*)d_in[29];
  const float* f_w2  = (const float*)d_in[30]; const float* f_b2  = (const float*)d_in[31];

  char* ws = (char*)d_ws;
  float* em   = (float*)(ws + OFF_EM);
  float* bqkv = (float*)(ws + OFF_BQKV);
  float* bckv = (float*)(ws + OFF_BCKV);
  bf16* xn    = (bf16*)(ws + OFF_XN);
  bf16* qkvb  = (bf16*)(ws + OFF_QKV);
  bf16* caqb  = (bf16*)(ws + OFF_CAQ);
  bf16* kvb   = (bf16*)(ws + OFF_KV);
  bf16* qb    = (bf16*)(ws + OFF_QB);
  bf16* kb    = (bf16*)(ws + OFF_KB);
  bf16* yb    = (bf16*)(ws + OFF_YB);
  bf16* ctxb  = (bf16*)(ws + OFF_CTX);
  bf16* wbuf  = (bf16*)(ws + OFF_WBUF);
  bf16* hb    = (bf16*)(ws + OFF_HB);
  float* xw   = (float*)d_out;   // residual stream lives in d_out

  const int M = BSZ * SLEN;   // 4096
  const int MC = BSZ * CTXL;  // 1024
  const float scl = 0.08838834764831845f;

#define TRANSO(W, Kd, Nd, noff) \
  transpose_w<<<dim3((Nd) / 64, (Kd) / 64), 256, 0, stream>>>(W, wbuf, Kd, Nd, noff)
#define GEMM(Am, Md, Nd, Kd, bias, oF, oB, res, sc, scs, rpb, mode) \
  gemm_bt<<<((Md) / 128) * ((Nd) / 128), 256, 0, stream>>>(Am, wbuf, bias, oF, oB, res, sc, scs, rpb, (Nd) / 128, Nd, Kd, mode)

  em_kernel<<<(BSZ * 6 * DIMX + 255) / 256, 256, 0, stream>>>(e, modu, em, BSZ * 6 * DIMX);
  cvt_kernel<<<(MC * DIMX / 8 + 255) / 256, 256, 0, stream>>>(context, ctxb, MC * DIMX / 8);
  packb_kernel<<<(3 * DIMX + 255) / 256, 256, 0, stream>>>(sa_bq, sa_bk, sa_bv, bqkv, 3 * DIMX);
  packb_kernel<<<(2 * DIMX + 255) / 256, 256, 0, stream>>>(ca_bk, ca_bv, nullptr, bckv, 2 * DIMX);

  // --- self attention ---
  ln_kernel<<<M, 256, 0, stream>>>(x, em + 1 * DIMX, em + 0 * DIMX, 6 * DIMX, 1.0f, SLEN, xn);

  TRANSO(sa_wq, DIMX, DIMX, 0);
  TRANSO(sa_wk, DIMX, DIMX, DIMX);
  TRANSO(sa_wv, DIMX, DIMX, 2 * DIMX);
  GEMM(xn, M, 3 * DIMX, DIMX, bqkv, nullptr, qkvb, nullptr, nullptr, 0, 1, 1);
  rms_rope_kernel<<<M, 256, 0, stream>>>(qkvb, 3 * DIMX, sa_nq, fcos, fsin, 1, qb);
  rms_rope_kernel<<<M, 256, 0, stream>>>((bf16*)((short*)qkvb + DIMX), 3 * DIMX, sa_nk, fcos, fsin, 1, kb);

  attn_kernel<<<dim3(SLEN / 64, BSZ * NHEADS), 256, 0, stream>>>(
      qb, kb, (bf16*)((short*)qkvb + 2 * DIMX), yb, SLEN, SLEN, DIMX, DIMX, 3 * DIMX, scl);

  TRANSO(sa_wo, DIMX, DIMX, 0);
  GEMM(yb, M, DIMX, DIMX, sa_bo, xw, nullptr, x, em + 2 * DIMX, 6 * DIMX, SLEN, 3);

  // --- cross attention ---
  ln_kernel<<<M, 256, 0, stream>>>(xw, n3_w, n3_b, 0, 0.0f, SLEN, xn);

  TRANSO(ca_wq, DIMX, DIMX, 0);
  GEMM(xn, M, DIMX, DIMX, ca_bq, nullptr, caqb, nullptr, nullptr, 0, 1, 1);
  rms_rope_kernel<<<M, 256, 0, stream>>>(caqb, DIMX, ca_nq, fcos, fsin, 0, qb);

  TRANSO(ca_wk, DIMX, DIMX, 0);
  TRANSO(ca_wv, DIMX, DIMX, DIMX);
  GEMM(ctxb, MC, 2 * DIMX, DIMX, bckv, nullptr, kvb, nullptr, nullptr, 0, 1, 1);
  rms_rope_kernel<<<MC, 256, 0, stream>>>(kvb, 2 * DIMX, ca_nk, fcos, fsin, 0, kb);

  attn_kernel<<<dim3(SLEN / 64, BSZ * NHEADS), 256, 0, stream>>>(
      qb, kb, (bf16*)((short*)kvb + DIMX), yb, SLEN, CTXL, DIMX, DIMX, 2 * DIMX, scl);

  TRANSO(ca_wo, DIMX, DIMX, 0);
  GEMM(yb, M, DIMX, DIMX, ca_bo, xw, nullptr, xw, nullptr, 0, SLEN, 3);

  // --- FFN ---
  ln_kernel<<<M, 256, 0, stream>>>(xw, em + 4 * DIMX, em + 3 * DIMX, 6 * DIMX, 1.0f, SLEN, xn);

  TRANSO(f_w1, DIMX, FFND, 0);
  GEMM(xn, M, FFND, DIMX, f_b1, nullptr, hb, nullptr, nullptr, 0, 1, 2);

  TRANSO(f_w2, FFND, DIMX, 0);
  GEMM(hb, M, DIMX, FFND, f_b2, xw, nullptr, xw, em + 5 * DIMX, 6 * DIMX, SLEN, 3);
}